// Round 2
// baseline (134.805 us; speedup 1.0000x reference)
//
#include <hip/hip_runtime.h>
#include <cstdint>
#include <cstddef>

// Problem constants
#define BB 4
#define NN 20000
#define KK 16
#define MM 9
#define CC 64
#define OO 64
#define BN (BB*NN)       // 80000 nodes
#define MC (MM*CC)       // 576 flattened reduction dim
#define NKS (MC/32)      // 18 K-steps in Phase C
#define NCH 625          // 32-node chunks per batch

typedef _Float16 f16x8 __attribute__((ext_vector_type(8)));
typedef _Float16 f16x4 __attribute__((ext_vector_type(4)));
typedef __fp16   fp16v2 __attribute__((ext_vector_type(2)));   // pkrtz return type
typedef float    f32x4 __attribute__((ext_vector_type(4)));
typedef unsigned short u16;
typedef unsigned int   u32;

union Hcv { _Float16 h; u16 u; };
__device__ __forceinline__ u16 f2h(float f) { Hcv t; t.h = (_Float16)f; return t.u; }

// ---------------------------------------------------------------------------
// Pre-pass (slimmed): uxvx GEMM is GONE (logits now computed in fused from the
// gathered f16 rows). blocks <1250: x -> xh f16 cast. 1250..1285: W -> wfb2
// fragment swizzle. 1286: u/v -> A-fragment tables (uvfa) + zero-pad m>=9.
// ---------------------------------------------------------------------------
__global__ __launch_bounds__(256) void pre_kernel(
    const float* __restrict__ x, const float* __restrict__ W,
    const float* __restrict__ u, const float* __restrict__ v,
    u16* __restrict__ xh, u16* __restrict__ wfb2, u16* __restrict__ uvfa)
{
    const int bid = blockIdx.x;
    if (bid == 1286) {                        // uv A-frag tables: 2048 u16
        int i0 = threadIdx.x * 8;
        u16 w8[8];
        #pragma unroll
        for (int tt = 0; tt < 8; ++tt) {
            int i = i0 + tt;
            int t = i >> 10, l = (i >> 4) & 63, s = (i >> 3) & 1, j = i & 7;
            int m = l & 15, hh = l >> 4;
            const float* src = t ? v : u;
            float val = (m < 9) ? src[m * 64 + s * 32 + hh * 8 + j] : 0.f;
            w8[tt] = f2h(val);
        }
        *(ushort4*)(uvfa + i0)     = *(ushort4*)(w8);
        *(ushort4*)(uvfa + i0 + 4) = *(ushort4*)(w8 + 4);
        return;
    }
    if (bid >= 1250) {                        // W swizzle: 36*1024 = 36864 elems
        int base = (bid - 1250) * 1024 + threadIdx.x * 4;
        ushort4 wv;
        u16* wp = (u16*)&wv;
        #pragma unroll
        for (int t = 0; t < 4; ++t) {
            int i = base + t;
            int j = i & 7, o = (i >> 3) & 63, l2 = (i >> 9) & 3, ks = i >> 11;
            int kf = ks * 32 + l2 * 8 + j;
            int m = kf >> 6, cc2 = kf & 63;
            wp[t] = f2h(W[m * 4096 + o * 64 + cc2]);
        }
        *(ushort4*)(wfb2 + base) = wv;
        return;
    }
    // x -> xh f16 cast, 64 nodes per block
    const int wave = threadIdx.x >> 6, lane = threadIdx.x & 63;
    const int lr = lane & 15, lhi = lane >> 4;
    const int t0n = bid * 64 + wave * 16;
    const float* xr = x + (size_t)(t0n + lr) * 64 + lhi * 8;
    float xf[16];
    *(float4*)(xf + 0)  = *(const float4*)(xr + 0);
    *(float4*)(xf + 4)  = *(const float4*)(xr + 4);
    *(float4*)(xf + 8)  = *(const float4*)(xr + 32);
    *(float4*)(xf + 12) = *(const float4*)(xr + 36);
    union { u16 us[8]; ushort4 s4[2]; } H0, H1;
    #pragma unroll
    for (int i = 0; i < 8; ++i) {
        H0.us[i] = f2h(xf[i]);
        H1.us[i] = f2h(xf[8 + i]);
    }
    u16* xw = xh + (size_t)(t0n + lr) * 64 + lhi * 8;
    *(ushort4*)(xw)          = H0.s4[0];
    *(ushort4*)(xw + 4)      = H0.s4[1];
    *(ushort4*)(xw + 32)     = H1.s4[0];
    *(ushort4*)(xw + 32 + 4) = H1.s4[1];
}

// ---------------------------------------------------------------------------
// Fused, 32-node blocks (2 tiles), ONE barrier, merged Phase C with W reuse:
//   - logits via MFMA on the SAME gathered rows Bcomp uses:
//       logits^T[m,k] = v.X_k + u.x_own (broadcast B), D: col=k=lr, row=m=lhi*4+reg
//   - softmax over m: 3 in-reg fmax + shfl_xor(16,32); q packed b64 into a
//     512B/node subtile laid out so ds_read_b64_tr_b16 yields the exact
//     16x16x16 B-fragment (content[p]=q[k][m], p = m + (k&3)*16 + (k>>2)*64).
//   - Phase C: bfrag loaded ONCE per ks, feeds both tiles (halves W L2 traffic).
// LDS 53248 B -> 3 blocks/CU (R0/R1 proved occupancy-insensitivity).
// Layouts (m89/m101/m121-128 verified): 16x16x32: A row=lane&15,
// k=(lane>>4)*8+j; B mirrors with col=lane&15; D col=lane&15, row=(lane>>4)*4+reg.
// ---------------------------------------------------------------------------
__global__ __launch_bounds__(256, 3) void fused_kernel(
    const u16* __restrict__ xh, const int* __restrict__ adj,
    const u16* __restrict__ wfb2, const u16* __restrict__ uvfa,
    const float* __restrict__ cvec, const float* __restrict__ bias,
    float* __restrict__ out)
{
    __shared__ __align__(16) u16 qlds[32 * 256];    // 16384 B (512B/node subtile)
    __shared__ __align__(16) u16 slds[72 * 32 * 8]; // 36864 B
    const int bid = blockIdx.x;
    const int grp = bid & 7;                        // XCD id (round-robin)
    const int b = grp >> 1;                         // batch owned by XCD pair
    const int chunk = (bid >> 3) * 2 + (grp & 1);
    if (chunk >= NCH) return;                       // 4 pad blocks exit
    const int tid = threadIdx.x, wave = tid >> 6, lane = tid & 63;
    const int lr = lane & 15, lhi = lane >> 4;
    const int node0 = b * NN + chunk * 32;
    const u16* xhb = xh + ((size_t)(b * NN) << 6);

    int jjA[2];
    jjA[0] = adj[(size_t)node0 * KK + tid];         // tile0
    jjA[1] = adj[(size_t)node0 * KK + 256 + tid];   // tile1

    // ---- gather xh rows for BOTH tiles (issued up front, max MLP) ----
    f16x8 gLo[2][4], gHi[2][4];
    #pragma unroll
    for (int t = 0; t < 2; ++t)
        #pragma unroll
        for (int g2 = 0; g2 < 4; ++g2) {
            int e = __builtin_amdgcn_ds_bpermute((g2 * 16 + lr) * 4, jjA[t]);
            int erow = ((e > 0) ? e : 1) - 1;       // pad -> row 0 (q=0 kills)
            const u16* rp = xhb + ((size_t)erow << 6) + lhi * 8;
            gLo[t][g2] = *(const f16x8*)(rp);
            gHi[t][g2] = *(const f16x8*)(rp + 32);
        }

    // ---- constant fragments ----
    const u16* up = uvfa + lane * 16;
    const f16x8 uAlo = *(const f16x8*)(up);
    const f16x8 uAhi = *(const f16x8*)(up + 8);
    const f16x8 vAlo = *(const f16x8*)(up + 1024);
    const f16x8 vAhi = *(const f16x8*)(up + 1024 + 8);
    float cv[4];
    #pragma unroll
    for (int r = 0; r < 4; ++r) { int m = lhi * 4 + r; cv[r] = (m < 9) ? cvec[m] : 0.f; }

    // identity-selector B-frags for the transpose-MFMA (Bcomp)
    f16x8 idf[2];
    #pragma unroll
    for (int s = 0; s < 2; ++s) {
        union { u16 us[8]; f16x8 v; } t;
        #pragma unroll
        for (int j = 0; j < 8; ++j)
            t.us[j] = (lhi * 8 + j == s * 16 + lr) ? (u16)0x3C00 : (u16)0;
        idf[s] = t.v;
    }

    const int o0 = wave * 16;
    const float bv = bias[o0 + lr];
    const u32 qbase = (u32)(size_t)qlds;   // LDS offset (aperture hi-bits truncate)

    #pragma unroll
    for (int t = 0; t < 2; ++t) {
        unsigned long long bal = __ballot(jjA[t] != 0);
        // ---- Phase A: logits MFMA + softmax + q -> qlds ----
        #pragma unroll
        for (int g2 = 0; g2 < 4; ++g2) {
            const int nd = t * 16 + wave * 4 + g2;
            const u16* orp = xh + ((size_t)(node0 + nd) << 6) + lhi * 8;
            f16x8 oLo = *(const f16x8*)(orp);
            f16x8 oHi = *(const f16x8*)(orp + 32);
            f32x4 acc = {0.f, 0.f, 0.f, 0.f};
            acc = __builtin_amdgcn_mfma_f32_16x16x32_f16(vAlo, gLo[t][g2], acc, 0, 0, 0);
            acc = __builtin_amdgcn_mfma_f32_16x16x32_f16(vAhi, gHi[t][g2], acc, 0, 0, 0);
            acc = __builtin_amdgcn_mfma_f32_16x16x32_f16(uAlo, oLo, acc, 0, 0, 0);
            acc = __builtin_amdgcn_mfma_f32_16x16x32_f16(uAhi, oHi, acc, 0, 0, 0);
            // softmax over m (regs+lhi), per (node, k=lr)
            u32 field = (u32)(bal >> (g2 * 16)) & 0xffffu;
            int  deg  = __popc(field);
            float inv = (deg > 0) ? __fdividef(1.0f, (float)deg) : 0.0f;
            int kbit = (field >> lr) & 1;
            float lm[4];
            #pragma unroll
            for (int r = 0; r < 4; ++r)
                lm[r] = (lhi * 4 + r < 9) ? (acc[r] + cv[r]) : -1e30f;
            float mx = fmaxf(fmaxf(lm[0], lm[1]), fmaxf(lm[2], lm[3]));
            mx = fmaxf(mx, __shfl_xor(mx, 16));
            mx = fmaxf(mx, __shfl_xor(mx, 32));
            float p0 = __expf(lm[0] - mx), p1 = __expf(lm[1] - mx);
            float p2 = __expf(lm[2] - mx), p3 = __expf(lm[3] - mx);
            float S = p0 + p1 + p2 + p3;
            S += __shfl_xor(S, 16);
            S += __shfl_xor(S, 32);
            float qsc = kbit ? __fdividef(inv, S) : 0.0f;
            union { fp16v2 h2[2]; uint2 u2; } qp;
            qp.h2[0] = __builtin_amdgcn_cvt_pkrtz(p0 * qsc, p1 * qsc);
            qp.h2[1] = __builtin_amdgcn_cvt_pkrtz(p2 * qsc, p3 * qsc);
            // content[p]=q[k][m], p = m + (k&3)*16 + (k>>2)*64 ; regs are m0..m3
            *(uint2*)(qlds + nd * 256 + lhi * 4 + (lr & 3) * 16 + (lr >> 2) * 64) = qp.u2;
        }
        asm volatile("s_waitcnt lgkmcnt(0)" ::: "memory");  // q writes retired
        // ---- hardware-transpose read: qf[g2] = B-frag (col=m=lr, k=lhi*4+j) ----
        f16x4 qf[4];
        {
            u32 qa = qbase + (u32)((t * 16 + wave * 4) * 512) + (u32)(lane * 8);
            asm volatile("ds_read_b64_tr_b16 %0, %1 offset:0"    : "=v"(qf[0]) : "v"(qa) : "memory");
            asm volatile("ds_read_b64_tr_b16 %0, %1 offset:512"  : "=v"(qf[1]) : "v"(qa) : "memory");
            asm volatile("ds_read_b64_tr_b16 %0, %1 offset:1024" : "=v"(qf[2]) : "v"(qa) : "memory");
            asm volatile("ds_read_b64_tr_b16 %0, %1 offset:1536" : "=v"(qf[3]) : "v"(qa) : "memory");
            asm volatile("s_waitcnt lgkmcnt(0)" ::: "memory");
            __builtin_amdgcn_sched_barrier(0);              // rule #18
        }
        // ---- Bcomp -> slds (chunked + XOR-swizzled by m) ----
        #pragma unroll
        for (int g2 = 0; g2 < 4; ++g2) {
            const int rnode = t * 16 + wave * 4 + g2;
            #pragma unroll
            for (int cc = 0; cc < 4; ++cc) {
                f32x4 xt = {0.f, 0.f, 0.f, 0.f};
                xt = __builtin_amdgcn_mfma_f32_16x16x32_f16(
                         (cc < 2) ? gLo[t][g2] : gHi[t][g2], idf[cc & 1], xt, 0, 0, 0);
                union { fp16v2 h2[2]; f16x4 h4; } at;
                at.h2[0] = __builtin_amdgcn_cvt_pkrtz(xt[0], xt[1]);
                at.h2[1] = __builtin_amdgcn_cvt_pkrtz(xt[2], xt[3]);
                f32x4 d2 = {0.f, 0.f, 0.f, 0.f};
                d2 = __builtin_amdgcn_mfma_f32_16x16x16f16(at.h4, qf[g2], d2, 0, 0, 0);
                if (lr < 9) {
                    u32 lo = __builtin_amdgcn_perm((u32)f2h(d2[1]), (u32)f2h(d2[0]), 0x05040100u);
                    u32 hi = __builtin_amdgcn_perm((u32)f2h(d2[3]), (u32)f2h(d2[2]), 0x05040100u);
                    // kf = lr*64 + cc*16 + lhi*4 ; q = kf>>3 ; m = kf>>6 = lr
                    int q_ = lr * 8 + cc * 2 + (lhi >> 1);
                    int idx = (((q_ * 32 + rnode) << 3) ^ ((lr & 7) << 3)) + (lhi & 1) * 4;
                    *(uint2*)(slds + idx) = make_uint2(lo, hi);
                }
            }
        }
    }
    __syncthreads();

    // ---- Phase C (merged, W reused for both tiles) ----
    f32x4 a0 = {0.f, 0.f, 0.f, 0.f}, a1 = {0.f, 0.f, 0.f, 0.f};
    #pragma unroll
    for (int ks = 0; ks < NKS; ++ks) {
        int q_ = ks * 4 + lhi;                      // m = q_>>3 (wave-uniform per ks)
        int sw = ((q_ >> 3) & 7) << 3;
        f16x8 af0 = *(const f16x8*)(slds + ((((q_ * 32) + lr) << 3) ^ sw));
        f16x8 af1 = *(const f16x8*)(slds + ((((q_ * 32) + 16 + lr) << 3) ^ sw));
        f16x8 bf  = *(const f16x8*)(wfb2 + (size_t)(q_ * 64 + o0 + lr) * 8);
        a0 = __builtin_amdgcn_mfma_f32_16x16x32_f16(af0, bf, a0, 0, 0, 0);
        a1 = __builtin_amdgcn_mfma_f32_16x16x32_f16(af1, bf, a1, 0, 0, 0);
    }
    #pragma unroll
    for (int r = 0; r < 4; ++r) {
        out[(size_t)(node0 + lhi * 4 + r) * OO + o0 + lr]      = a0[r] + bv;
        out[(size_t)(node0 + 16 + lhi * 4 + r) * OO + o0 + lr] = a1[r] + bv;
    }
}

// ---------------------------------------------------------------------------
extern "C" void kernel_launch(void* const* d_in, const int* in_sizes, int n_in,
                              void* d_out, int out_size, void* d_ws, size_t ws_size,
                              hipStream_t stream)
{
    const float* x   = (const float*)d_in[0];
    const int*   adj = (const int*)  d_in[1];
    const float* W   = (const float*)d_in[2];
    const float* b   = (const float*)d_in[3];
    const float* u   = (const float*)d_in[4];
    const float* v   = (const float*)d_in[5];
    const float* c   = (const float*)d_in[6];
    float* out = (float*)d_out;

    // workspace: xh f16 [BN*64] | wfb2 f16 [36864] | uvfa f16 [2048]  (~10.3 MB)
    u16* xh   = (u16*)d_ws;
    u16* wfb2 = xh + (size_t)BN * CC;
    u16* uvfa = wfb2 + 36864;

    pre_kernel<<<1287, 256, 0, stream>>>(x, W, u, v, xh, wfb2, uvfa);
    fused_kernel<<<2504, 256, 0, stream>>>(xh, adj, wfb2, uvfa, c, b, out);
}